// Round 17
// baseline (420.555 us; speedup 1.0000x reference)
//
#include <hip/hip_runtime.h>

// 2-layer LSTM (B=4096, T=512, H=50) + FC head.
// R17 vs R16 (435 us steady, ~70% issue-bound, stalls = barrier-aligned FIN
// chains): 4 waves/SIMD via 4-role split, FIN kept on 8 waves (trans/SIMD
// unchanged), light I-waves fill the FIN-chain stall windows.
//  16 waves (1024 thr): 4 L0 | 4 I0 (Wih1 ktile0) | 4 I1 (ktile1) | 4 R.
//  I0/I1 write f32 partials to PA/PB; R sums PA+PB in FIN.
//  bias pre-built as f32x4 MFMA C-initializers (no per-step movs).
//  Reg audit: L0 ~92, I ~60, R ~120 unified <= 128 = 512/4;
//  amdgpu_waves_per_eu(4,4) states the contract (R7: max-bound honored).
//  WRITE_SIZE = spill sentinel (R10's failure mode).
// Cadence/parities verbatim from R16 (proven, absmax bit-identical).

typedef __attribute__((ext_vector_type(8))) _Float16 half8;
typedef __attribute__((ext_vector_type(4))) float f32x4;

#define LOG2E 1.44269504088896340736f

__device__ __forceinline__ float rcp_(float x) { return __builtin_amdgcn_rcpf(x); }
__device__ __forceinline__ float exp2_(float x) { return __builtin_amdgcn_exp2f(x); }
__device__ __forceinline__ float sigm(float x) {
  return rcp_(1.f + exp2_(-LOG2E * x));
}
__device__ __forceinline__ float tanh_(float x) {
  return 1.f - 2.f * rcp_(1.f + exp2_(2.f * LOG2E * x));
}
__device__ __forceinline__ f32x4 mfma16(half8 a, half8 b, f32x4 c) {
  return __builtin_amdgcn_mfma_f32_16x16x32_f16(a, b, c, 0, 0, 0);
}

union ABu16 { uint4 u; half8 v; };
__device__ __forceinline__ half8 rdfrag(const _Float16* p) {
  ABu16 t;
  t.u = *(const uint4*)p;
  return t.v;
}

// Single-f16 B-fragment of W (50x50 logical) for output column (n,gate);
// k = kbase + 16*(e>>2) + 4*lg + (e&3).
__device__ __forceinline__ half8 loadW1(const float* __restrict__ W, int n,
                                        int gate, int kbase, int lg) {
  half8 r;
#pragma unroll
  for (int e = 0; e < 8; ++e) {
    const int k = kbase + 16 * (e >> 2) + 4 * lg + (e & 3);
    const bool v = (n < 50) && (k < 50);
    r[e] = (_Float16)(v ? W[(gate * 50 + n) * 50 + k] : 0.f);
  }
  return r;
}

__global__ __launch_bounds__(1024)
__attribute__((amdgpu_waves_per_eu(4, 4)))
void lstm2_kernel(
    const float* __restrict__ x,
    const float* __restrict__ Wih0, const float* __restrict__ Whh0,
    const float* __restrict__ bih0, const float* __restrict__ bhh0,
    const float* __restrict__ Wih1, const float* __restrict__ Whh1,
    const float* __restrict__ bih1, const float* __restrict__ bhh1,
    const float* __restrict__ fcW, const float* __restrict__ fcb,
    float* __restrict__ out) {
  const int tid = threadIdx.x;
  const int lane = tid & 63;
  const int wv = tid >> 6;       // wave 0..15
  const int role = wv >> 2;      // 0=L0, 1=I0, 2=I1, 3=R
  const int wg = wv & 3;         // unit-group within role
  const int lg = lane >> 4;      // 0..3 (k-slice / batch-group)
  const int l15 = lane & 15;
  const int bbase = blockIdx.x * 16;

  // h planes (f16): idx(u,b) = (u>>5)*512 + ((u>>2)&3)*128 + b*8 +
  // ((u>>4)&1)*4 + (u&3). A-frag for k-tile kt = b128 at [kt*512 + 8*lane].
  __shared__ __align__(16) _Float16 H0[2][1024], H1[2][1024];
  // f32 partials (I0 -> PA, I1 -> PB): [parity][gate*1024 + wg*256 + lane*4]
  __shared__ __align__(16) float PA[2][4096], PB[2][4096];
  __shared__ float xs2[64][16];   // x chunk: [t within chunk][batch]
  __shared__ float ldspad[1600];  // pad -> ~82.6 KB total -> 1 block/CU

  ((volatile float*)ldspad)[tid & 1023] = 0.f;

  {  // zero both parities of both h planes (1024 uints, 1024 threads)
    ((unsigned int*)H0)[tid] = 0u;
    ((unsigned int*)H1)[tid] = 0u;
  }

  const int lane8 = lane * 8;   // f16 index of this lane's b128 A-frag slot
  const int u = 16 * wg + l15;  // this lane's output unit
  const bool uv = (u < 50);
  // h write base for (u, batches 4lg..4lg+3): +8 per batch row
  const int woff = ((u >> 5) << 9) + (((u >> 2) & 3) << 7) + ((4 * lg) << 3) +
                   (((u >> 4) & 1) << 2) + (u & 3);
  const int pidx = wg * 256 + lane * 4;  // f32 index within a gate plane

#define STAGE(c)                                                        \
  {                                                                     \
    const int b_ = tid >> 4, fg_ = tid & 15;                            \
    const float4 v_ = *(const float4*)&x[(size_t)(bbase + b_) * 512 +   \
                                         (c) * 64 + 4 * fg_];           \
    xs2[4 * fg_ + 0][b_] = v_.x; xs2[4 * fg_ + 1][b_] = v_.y;           \
    xs2[4 * fg_ + 2][b_] = v_.z; xs2[4 * fg_ + 3][b_] = v_.w;           \
  }

  if (role == 0) {
    // ============ L0: h0[s] = FIN(Whh0*h0[s-1] + x*wx + b) ============
    half8 W0_0, W1_0, W0_1, W1_1, W0_2, W1_2, W0_3, W1_3;
    float bi_0 = 0.f, bi_1 = 0.f, bi_2 = 0.f, bi_3 = 0.f;
    float wx_0 = 0.f, wx_1 = 0.f, wx_2 = 0.f, wx_3 = 0.f;
    W0_0 = loadW1(Whh0, u, 0, 0, lg);  W1_0 = loadW1(Whh0, u, 0, 32, lg);
    W0_1 = loadW1(Whh0, u, 1, 0, lg);  W1_1 = loadW1(Whh0, u, 1, 32, lg);
    W0_2 = loadW1(Whh0, u, 2, 0, lg);  W1_2 = loadW1(Whh0, u, 2, 32, lg);
    W0_3 = loadW1(Whh0, u, 3, 0, lg);  W1_3 = loadW1(Whh0, u, 3, 32, lg);
    if (uv) {
      bi_0 = bih0[0 * 50 + u] + bhh0[0 * 50 + u]; wx_0 = Wih0[0 * 50 + u];
      bi_1 = bih0[1 * 50 + u] + bhh0[1 * 50 + u]; wx_1 = Wih0[1 * 50 + u];
      bi_2 = bih0[2 * 50 + u] + bhh0[2 * 50 + u]; wx_2 = Wih0[2 * 50 + u];
      bi_3 = bih0[3 * 50 + u] + bhh0[3 * 50 + u]; wx_3 = Wih0[3 * 50 + u];
    }
    const f32x4 b4_0 = {bi_0, bi_0, bi_0, bi_0};
    const f32x4 b4_1 = {bi_1, bi_1, bi_1, bi_1};
    const f32x4 b4_2 = {bi_2, bi_2, bi_2, bi_2};
    const f32x4 b4_3 = {bi_3, bi_3, bi_3, bi_3};
    float cc0 = 0.f, cc1 = 0.f, cc2 = 0.f, cc3 = 0.f;

#define FIN0(r, xr, WPc)                                              \
    { const float i_ = sigm(ai[r] + (xr) * wx_0);                     \
      const float ff = sigm(af[r] + (xr) * wx_1);                     \
      const float g_ = tanh_(ag[r] + (xr) * wx_2);                    \
      const float o_ = sigm(ao[r] + (xr) * wx_3);                     \
      cc##r = ff * cc##r + i_ * g_;                                   \
      H0[WPc][woff + 8 * (r)] = (_Float16)(o_ * tanh_(cc##r)); }

#define L0STEP(RP, WP, tm)                                            \
    { const half8 f0 = rdfrag(&H0[RP][lane8]);                        \
      const half8 f1 = rdfrag(&H0[RP][512 + lane8]);                  \
      f32x4 ai = mfma16(f0, W0_0, b4_0); ai = mfma16(f1, W1_0, ai);   \
      f32x4 af = mfma16(f0, W0_1, b4_1); af = mfma16(f1, W1_1, af);   \
      f32x4 ag = mfma16(f0, W0_2, b4_2); ag = mfma16(f1, W1_2, ag);   \
      f32x4 ao = mfma16(f0, W0_3, b4_3); ao = mfma16(f1, W1_3, ao);   \
      const float4 xv = *(const float4*)&xs2[tm][4 * lg];             \
      FIN0(0, xv.x, WP) FIN0(1, xv.y, WP)                             \
      FIN0(2, xv.z, WP) FIN0(3, xv.w, WP) }

    for (int it = 0; it <= 256; ++it) {
      if ((it & 31) == 0 && it < 256) { STAGE(it >> 5) __syncthreads(); }
      if (it < 256) L0STEP(1, 0, ((2 * it) & 63))
      __syncthreads();
      if (it < 256) L0STEP(0, 1, ((2 * it + 1) & 63))
      __syncthreads();
    }
  } else if (role == 1) {
    // ============ I0: PA[s-1] = Wih1(ktile0) * h0[s-1] ============
    half8 I0_0 = loadW1(Wih1, u, 0, 0, lg);
    half8 I0_1 = loadW1(Wih1, u, 1, 0, lg);
    half8 I0_2 = loadW1(Wih1, u, 2, 0, lg);
    half8 I0_3 = loadW1(Wih1, u, 3, 0, lg);

#define I0STEP(RP, WPp)                                               \
    { const half8 f0 = rdfrag(&H0[RP][lane8]);                        \
      const f32x4 z = {0.f, 0.f, 0.f, 0.f};                           \
      const f32x4 a0 = mfma16(f0, I0_0, z);                           \
      const f32x4 a1 = mfma16(f0, I0_1, z);                           \
      const f32x4 a2 = mfma16(f0, I0_2, z);                           \
      const f32x4 a3 = mfma16(f0, I0_3, z);                           \
      *(f32x4*)&PA[WPp][pidx]        = a0;                            \
      *(f32x4*)&PA[WPp][1024 + pidx] = a1;                            \
      *(f32x4*)&PA[WPp][2048 + pidx] = a2;                            \
      *(f32x4*)&PA[WPp][3072 + pidx] = a3; }

    for (int it = 0; it <= 256; ++it) {
      if ((it & 31) == 0 && it < 256) { __syncthreads(); }
      if (it >= 1) I0STEP(1, 1)
      __syncthreads();
      if (it < 256) I0STEP(0, 0)
      __syncthreads();
    }
  } else if (role == 2) {
    // ============ I1: PB[s-1] = Wih1(ktile1) * h0[s-1] ============
    half8 I1_0 = loadW1(Wih1, u, 0, 32, lg);
    half8 I1_1 = loadW1(Wih1, u, 1, 32, lg);
    half8 I1_2 = loadW1(Wih1, u, 2, 32, lg);
    half8 I1_3 = loadW1(Wih1, u, 3, 32, lg);

#define I1STEP(RP, WPp)                                               \
    { const half8 f1 = rdfrag(&H0[RP][512 + lane8]);                  \
      const f32x4 z = {0.f, 0.f, 0.f, 0.f};                           \
      const f32x4 a0 = mfma16(f1, I1_0, z);                           \
      const f32x4 a1 = mfma16(f1, I1_1, z);                           \
      const f32x4 a2 = mfma16(f1, I1_2, z);                           \
      const f32x4 a3 = mfma16(f1, I1_3, z);                           \
      *(f32x4*)&PB[WPp][pidx]        = a0;                            \
      *(f32x4*)&PB[WPp][1024 + pidx] = a1;                            \
      *(f32x4*)&PB[WPp][2048 + pidx] = a2;                            \
      *(f32x4*)&PB[WPp][3072 + pidx] = a3; }

    for (int it = 0; it <= 256; ++it) {
      if ((it & 31) == 0 && it < 256) { __syncthreads(); }
      if (it >= 1) I1STEP(1, 1)
      __syncthreads();
      if (it < 256) I1STEP(0, 0)
      __syncthreads();
    }
  } else {
    // ============ R: h1[s-2] = FIN(PA+PB[s-2] + Whh1*h1[s-3]) ============
    half8 R0_0, R1_0, R0_1, R1_1, R0_2, R1_2, R0_3, R1_3;
    float bi_0 = 0.f, bi_1 = 0.f, bi_2 = 0.f, bi_3 = 0.f;
    R0_0 = loadW1(Whh1, u, 0, 0, lg);  R1_0 = loadW1(Whh1, u, 0, 32, lg);
    R0_1 = loadW1(Whh1, u, 1, 0, lg);  R1_1 = loadW1(Whh1, u, 1, 32, lg);
    R0_2 = loadW1(Whh1, u, 2, 0, lg);  R1_2 = loadW1(Whh1, u, 2, 32, lg);
    R0_3 = loadW1(Whh1, u, 3, 0, lg);  R1_3 = loadW1(Whh1, u, 3, 32, lg);
    if (uv) {
      bi_0 = bih1[0 * 50 + u] + bhh1[0 * 50 + u];
      bi_1 = bih1[1 * 50 + u] + bhh1[1 * 50 + u];
      bi_2 = bih1[2 * 50 + u] + bhh1[2 * 50 + u];
      bi_3 = bih1[3 * 50 + u] + bhh1[3 * 50 + u];
    }
    const f32x4 b4_0 = {bi_0, bi_0, bi_0, bi_0};
    const f32x4 b4_1 = {bi_1, bi_1, bi_1, bi_1};
    const f32x4 b4_2 = {bi_2, bi_2, bi_2, bi_2};
    const f32x4 b4_3 = {bi_3, bi_3, bi_3, bi_3};
    float cc0 = 0.f, cc1 = 0.f, cc2 = 0.f, cc3 = 0.f;

#define FINR2(r, WH)                                                  \
    { const float i_ = sigm(ai[r] + pa0[r] + pb0[r]);                 \
      const float ff = sigm(af[r] + pa1[r] + pb1[r]);                 \
      const float g_ = tanh_(ag[r] + pa2[r] + pb2[r]);                \
      const float o_ = sigm(ao[r] + pa3[r] + pb3[r]);                 \
      cc##r = ff * cc##r + i_ * g_;                                   \
      H1[WH][woff + 8 * (r)] = (_Float16)(o_ * tanh_(cc##r)); }

#define RSTEP(PP, RH, WH)                                             \
    { const half8 g0 = rdfrag(&H1[RH][lane8]);                        \
      const half8 g1 = rdfrag(&H1[RH][512 + lane8]);                  \
      const f32x4 pa0 = *(const f32x4*)&PA[PP][pidx];                 \
      const f32x4 pa1 = *(const f32x4*)&PA[PP][1024 + pidx];          \
      const f32x4 pa2 = *(const f32x4*)&PA[PP][2048 + pidx];          \
      const f32x4 pa3 = *(const f32x4*)&PA[PP][3072 + pidx];          \
      const f32x4 pb0 = *(const f32x4*)&PB[PP][pidx];                 \
      const f32x4 pb1 = *(const f32x4*)&PB[PP][1024 + pidx];          \
      const f32x4 pb2 = *(const f32x4*)&PB[PP][2048 + pidx];          \
      const f32x4 pb3 = *(const f32x4*)&PB[PP][3072 + pidx];          \
      f32x4 ai = mfma16(g0, R0_0, b4_0); ai = mfma16(g1, R1_0, ai);   \
      f32x4 af = mfma16(g0, R0_1, b4_1); af = mfma16(g1, R1_1, af);   \
      f32x4 ag = mfma16(g0, R0_2, b4_2); ag = mfma16(g1, R1_2, ag);   \
      f32x4 ao = mfma16(g0, R0_3, b4_3); ao = mfma16(g1, R1_3, ao);   \
      FINR2(0, WH) FINR2(1, WH) FINR2(2, WH) FINR2(3, WH) }

    for (int it = 0; it <= 256; ++it) {
      if ((it & 31) == 0 && it < 256) { __syncthreads(); }
      if (it >= 1) RSTEP(0, 1, 0)
      __syncthreads();
      if (it >= 1) RSTEP(1, 0, 1)
      __syncthreads();
    }
  }

  // ---- FC head: out[b] = fc_b + sum_j fcW[j] * h1[511][b][j] (parity 1) ----
  if (tid < 16) {
    float s = fcb[0];
    for (int j = 0; j < 50; ++j) {
      const int idx = ((j >> 5) << 9) + (((j >> 2) & 3) << 7) + (tid << 3) +
                      (((j >> 4) & 1) << 2) + (j & 3);
      s += fcW[j] * (float)H1[1][idx];
    }
    out[bbase + tid] = s;
  }
}

extern "C" void kernel_launch(void* const* d_in, const int* in_sizes, int n_in,
                              void* d_out, int out_size, void* d_ws, size_t ws_size,
                              hipStream_t stream) {
  const float* x    = (const float*)d_in[0];
  const float* Wih0 = (const float*)d_in[1];
  const float* Whh0 = (const float*)d_in[2];
  const float* bih0 = (const float*)d_in[3];
  const float* bhh0 = (const float*)d_in[4];
  const float* Wih1 = (const float*)d_in[5];
  const float* Whh1 = (const float*)d_in[6];
  const float* bih1 = (const float*)d_in[7];
  const float* bhh1 = (const float*)d_in[8];
  const float* fcW  = (const float*)d_in[9];
  const float* fcb  = (const float*)d_in[10];
  float* out = (float*)d_out;

  const int B = out_size;          // 4096
  const int blocks = B / 16;       // 256
  lstm2_kernel<<<dim3(blocks), dim3(1024), 0, stream>>>(
      x, Wih0, Whh0, bih0, bhh0, Wih1, Whh1, bih1, bhh1, fcW, fcb, out);
}

// Round 18
// 389.563 us; speedup vs baseline: 1.0796x; 1.0796x over previous
//
#include <hip/hip_runtime.h>

// 2-layer LSTM (B=4096, T=512, H=50) + FC head.
// R18 = REVERT to R16 (the measured best: 435 us steady), after R17's
// 4-wave/SIMD variant regressed to 471 us.
// Final ledger: 21.5ms (R2 naive-spill) -> 3.56ms (fp32 VALU best) ->
// 1.125ms (MFMA bf16-pair) -> 537us (gate-major f16-pair) -> 435us
// (single-f16 weights + 3-stage pipeline). TLP sweep 2/3/4 waves/SIMD =
// 437/435/471: residual over the ~310us VALU-issue floor is per-step
// cross-wave h-exchange latency, not hideable by occupancy; trans-count
// reductions (R11 paired-rcp, R13 common-denominator) both regressed.
//  3-STAGE PIPELINE, 12 waves (768 thr) = 3 waves/SIMD:
//   role 0 (wv 0-3):  L0  computes h0[s]          (8 MFMA + FIN)
//   role 1 (wv 4-7):  I   computes P[s-1]=Wih1*h0 (8 MFMA, f32 partials->LDS)
//   role 2 (wv 8-11): R   computes h1[s-2]=FIN(P[s-2]+Whh1*h1[s-3])
//  One barrier/step; single-f16 weights (AGPR-resident); h = f16 plane
//  (quant floor absmax = 4.882812e-4); c fp32 in registers.

typedef __attribute__((ext_vector_type(8))) _Float16 half8;
typedef __attribute__((ext_vector_type(4))) float f32x4;

#define LOG2E 1.44269504088896340736f

__device__ __forceinline__ float rcp_(float x) { return __builtin_amdgcn_rcpf(x); }
__device__ __forceinline__ float exp2_(float x) { return __builtin_amdgcn_exp2f(x); }
__device__ __forceinline__ float sigm(float x) {
  return rcp_(1.f + exp2_(-LOG2E * x));
}
__device__ __forceinline__ float tanh_(float x) {
  return 1.f - 2.f * rcp_(1.f + exp2_(2.f * LOG2E * x));
}
__device__ __forceinline__ f32x4 mfma16(half8 a, half8 b, f32x4 c) {
  return __builtin_amdgcn_mfma_f32_16x16x32_f16(a, b, c, 0, 0, 0);
}

union ABu16 { uint4 u; half8 v; };
__device__ __forceinline__ half8 rdfrag(const _Float16* p) {
  ABu16 t;
  t.u = *(const uint4*)p;
  return t.v;
}

// Single-f16 B-fragment of W (50x50 logical) for output column (n,gate);
// k = kbase + 16*(e>>2) + 4*lg + (e&3).
__device__ __forceinline__ half8 loadW1(const float* __restrict__ W, int n,
                                        int gate, int kbase, int lg) {
  half8 r;
#pragma unroll
  for (int e = 0; e < 8; ++e) {
    const int k = kbase + 16 * (e >> 2) + 4 * lg + (e & 3);
    const bool v = (n < 50) && (k < 50);
    r[e] = (_Float16)(v ? W[(gate * 50 + n) * 50 + k] : 0.f);
  }
  return r;
}

__global__ __launch_bounds__(768) void lstm2_kernel(
    const float* __restrict__ x,
    const float* __restrict__ Wih0, const float* __restrict__ Whh0,
    const float* __restrict__ bih0, const float* __restrict__ bhh0,
    const float* __restrict__ Wih1, const float* __restrict__ Whh1,
    const float* __restrict__ bih1, const float* __restrict__ bhh1,
    const float* __restrict__ fcW, const float* __restrict__ fcb,
    float* __restrict__ out) {
  const int tid = threadIdx.x;
  const int lane = tid & 63;
  const int wv = tid >> 6;       // wave 0..11
  const int role = wv >> 2;      // 0 = L0, 1 = I, 2 = R
  const int wg = wv & 3;         // unit-group within role
  const int lg = lane >> 4;      // 0..3 (k-slice / batch-group)
  const int l15 = lane & 15;
  const int bbase = blockIdx.x * 16;

  // h planes (f16): idx(u,b) = (u>>5)*512 + ((u>>2)&3)*128 + b*8 +
  // ((u>>4)&1)*4 + (u&3). A-frag for k-tile kt = b128 at [kt*512 + 8*lane].
  __shared__ __align__(16) _Float16 H0[2][1024], H1[2][1024];
  // f32 partials: [parity][gate*1024 + wg*256 + lane*4] (lane-sequential b128)
  __shared__ __align__(16) float Pbuf[2][4096];
  __shared__ float xs2[64][16];    // x chunk: [t within chunk][batch]
  __shared__ float ldspad[10240];  // 40 KB pin -> 84 KB total -> 1 blk/CU

  ((volatile float*)ldspad)[tid] = 0.f;

  for (int i = tid; i < 1024; i += 768) {  // zero both parities of both planes
    ((unsigned int*)H0)[i] = 0u;
    ((unsigned int*)H1)[i] = 0u;
  }

  const int lane8 = lane * 8;   // f16 index of this lane's b128 A-frag slot
  const int u = 16 * wg + l15;  // this lane's output unit
  const bool uv = (u < 50);
  // h write base for (u, batches 4lg..4lg+3): +8 per batch row
  const int woff = ((u >> 5) << 9) + (((u >> 2) & 3) << 7) + ((4 * lg) << 3) +
                   (((u >> 4) & 1) << 2) + (u & 3);
  const int pidx = wg * 256 + lane * 4;  // f32 index within a gate plane

#define STAGE(c)                                                        \
  {                                                                     \
    const int b_ = tid >> 4, fg_ = tid & 15;                            \
    const float4 v_ = *(const float4*)&x[(size_t)(bbase + b_) * 512 +   \
                                         (c) * 64 + 4 * fg_];           \
    xs2[4 * fg_ + 0][b_] = v_.x; xs2[4 * fg_ + 1][b_] = v_.y;           \
    xs2[4 * fg_ + 2][b_] = v_.z; xs2[4 * fg_ + 3][b_] = v_.w;           \
  }

  if (role == 0) {
    // ============ L0 waves: h0[s] = FIN(Whh0*h0[s-1] + x*wx + b) ============
    half8 W0_0, W1_0, W0_1, W1_1, W0_2, W1_2, W0_3, W1_3;
    float bi_0 = 0.f, bi_1 = 0.f, bi_2 = 0.f, bi_3 = 0.f;
    float wx_0 = 0.f, wx_1 = 0.f, wx_2 = 0.f, wx_3 = 0.f;
    W0_0 = loadW1(Whh0, u, 0, 0, lg);  W1_0 = loadW1(Whh0, u, 0, 32, lg);
    W0_1 = loadW1(Whh0, u, 1, 0, lg);  W1_1 = loadW1(Whh0, u, 1, 32, lg);
    W0_2 = loadW1(Whh0, u, 2, 0, lg);  W1_2 = loadW1(Whh0, u, 2, 32, lg);
    W0_3 = loadW1(Whh0, u, 3, 0, lg);  W1_3 = loadW1(Whh0, u, 3, 32, lg);
    if (uv) {
      bi_0 = bih0[0 * 50 + u] + bhh0[0 * 50 + u]; wx_0 = Wih0[0 * 50 + u];
      bi_1 = bih0[1 * 50 + u] + bhh0[1 * 50 + u]; wx_1 = Wih0[1 * 50 + u];
      bi_2 = bih0[2 * 50 + u] + bhh0[2 * 50 + u]; wx_2 = Wih0[2 * 50 + u];
      bi_3 = bih0[3 * 50 + u] + bhh0[3 * 50 + u]; wx_3 = Wih0[3 * 50 + u];
    }
    float cc0 = 0.f, cc1 = 0.f, cc2 = 0.f, cc3 = 0.f;

#define FIN0(r, xr, WPc)                                              \
    { const float i_ = sigm(ai[r] + (xr) * wx_0);                     \
      const float ff = sigm(af[r] + (xr) * wx_1);                     \
      const float g_ = tanh_(ag[r] + (xr) * wx_2);                    \
      const float o_ = sigm(ao[r] + (xr) * wx_3);                     \
      cc##r = ff * cc##r + i_ * g_;                                   \
      H0[WPc][woff + 8 * (r)] = (_Float16)(o_ * tanh_(cc##r)); }

#define L0STEP(RP, WP, tm)                                            \
    { const half8 f0 = rdfrag(&H0[RP][lane8]);                        \
      const half8 f1 = rdfrag(&H0[RP][512 + lane8]);                  \
      f32x4 ai = {bi_0, bi_0, bi_0, bi_0};                            \
      f32x4 af = {bi_1, bi_1, bi_1, bi_1};                            \
      f32x4 ag = {bi_2, bi_2, bi_2, bi_2};                            \
      f32x4 ao = {bi_3, bi_3, bi_3, bi_3};                            \
      ai = mfma16(f0, W0_0, ai); ai = mfma16(f1, W1_0, ai);           \
      af = mfma16(f0, W0_1, af); af = mfma16(f1, W1_1, af);           \
      ag = mfma16(f0, W0_2, ag); ag = mfma16(f1, W1_2, ag);           \
      ao = mfma16(f0, W0_3, ao); ao = mfma16(f1, W1_3, ao);           \
      const float4 xv = *(const float4*)&xs2[tm][4 * lg];             \
      FIN0(0, xv.x, WP) FIN0(1, xv.y, WP)                             \
      FIN0(2, xv.z, WP) FIN0(3, xv.w, WP) }

    for (int it = 0; it <= 256; ++it) {
      if ((it & 31) == 0 && it < 256) { STAGE(it >> 5) __syncthreads(); }
      if (it < 256) L0STEP(1, 0, ((2 * it) & 63))       // even s=2it
      __syncthreads();
      if (it < 256) L0STEP(0, 1, ((2 * it + 1) & 63))   // odd s=2it+1
      __syncthreads();
    }
  } else if (role == 1) {
    // ============ I waves: P[s-1] = Wih1 * h0[s-1] (f32 partials) ============
    half8 I0_0, I1_0, I0_1, I1_1, I0_2, I1_2, I0_3, I1_3;
    I0_0 = loadW1(Wih1, u, 0, 0, lg);  I1_0 = loadW1(Wih1, u, 0, 32, lg);
    I0_1 = loadW1(Wih1, u, 1, 0, lg);  I1_1 = loadW1(Wih1, u, 1, 32, lg);
    I0_2 = loadW1(Wih1, u, 2, 0, lg);  I1_2 = loadW1(Wih1, u, 2, 32, lg);
    I0_3 = loadW1(Wih1, u, 3, 0, lg);  I1_3 = loadW1(Wih1, u, 3, 32, lg);

#define ISTEP(RP, WPp)                                                \
    { const half8 f0 = rdfrag(&H0[RP][lane8]);                        \
      const half8 f1 = rdfrag(&H0[RP][512 + lane8]);                  \
      f32x4 a0 = {0.f, 0.f, 0.f, 0.f};                                \
      f32x4 a1 = a0, a2 = a0, a3 = a0;                                \
      a0 = mfma16(f0, I0_0, a0); a0 = mfma16(f1, I1_0, a0);           \
      a1 = mfma16(f0, I0_1, a1); a1 = mfma16(f1, I1_1, a1);           \
      a2 = mfma16(f0, I0_2, a2); a2 = mfma16(f1, I1_2, a2);           \
      a3 = mfma16(f0, I0_3, a3); a3 = mfma16(f1, I1_3, a3);           \
      *(f32x4*)&Pbuf[WPp][pidx]        = a0;                          \
      *(f32x4*)&Pbuf[WPp][1024 + pidx] = a1;                          \
      *(f32x4*)&Pbuf[WPp][2048 + pidx] = a2;                          \
      *(f32x4*)&Pbuf[WPp][3072 + pidx] = a3; }

    for (int it = 0; it <= 256; ++it) {
      if ((it & 31) == 0 && it < 256) { __syncthreads(); }
      if (it >= 1) ISTEP(1, 1)      // even s: P[s-1] (odd idx), rd h0 par1
      __syncthreads();
      if (it < 256) ISTEP(0, 0)     // odd s: P[s-1] (even idx), rd h0 par0
      __syncthreads();
    }
  } else {
    // ============ R waves: h1[s-2] = FIN(P[s-2] + Whh1*h1[s-3]) ============
    half8 R0_0, R1_0, R0_1, R1_1, R0_2, R1_2, R0_3, R1_3;
    float bi_0 = 0.f, bi_1 = 0.f, bi_2 = 0.f, bi_3 = 0.f;
    R0_0 = loadW1(Whh1, u, 0, 0, lg);  R1_0 = loadW1(Whh1, u, 0, 32, lg);
    R0_1 = loadW1(Whh1, u, 1, 0, lg);  R1_1 = loadW1(Whh1, u, 1, 32, lg);
    R0_2 = loadW1(Whh1, u, 2, 0, lg);  R1_2 = loadW1(Whh1, u, 2, 32, lg);
    R0_3 = loadW1(Whh1, u, 3, 0, lg);  R1_3 = loadW1(Whh1, u, 3, 32, lg);
    if (uv) {
      bi_0 = bih1[0 * 50 + u] + bhh1[0 * 50 + u];
      bi_1 = bih1[1 * 50 + u] + bhh1[1 * 50 + u];
      bi_2 = bih1[2 * 50 + u] + bhh1[2 * 50 + u];
      bi_3 = bih1[3 * 50 + u] + bhh1[3 * 50 + u];
    }
    float cc0 = 0.f, cc1 = 0.f, cc2 = 0.f, cc3 = 0.f;

#define FINR2(r, WH)                                                  \
    { const float i_ = sigm(ai[r] + p0[r]);                           \
      const float ff = sigm(af[r] + p1[r]);                           \
      const float g_ = tanh_(ag[r] + p2[r]);                          \
      const float o_ = sigm(ao[r] + p3[r]);                           \
      cc##r = ff * cc##r + i_ * g_;                                   \
      H1[WH][woff + 8 * (r)] = (_Float16)(o_ * tanh_(cc##r)); }

#define RSTEP(PP, RH, WH)                                             \
    { const half8 g0 = rdfrag(&H1[RH][lane8]);                        \
      const half8 g1 = rdfrag(&H1[RH][512 + lane8]);                  \
      const f32x4 p0 = *(const f32x4*)&Pbuf[PP][pidx];                \
      const f32x4 p1 = *(const f32x4*)&Pbuf[PP][1024 + pidx];         \
      const f32x4 p2 = *(const f32x4*)&Pbuf[PP][2048 + pidx];         \
      const f32x4 p3 = *(const f32x4*)&Pbuf[PP][3072 + pidx];         \
      f32x4 ai = {bi_0, bi_0, bi_0, bi_0};                            \
      f32x4 af = {bi_1, bi_1, bi_1, bi_1};                            \
      f32x4 ag = {bi_2, bi_2, bi_2, bi_2};                            \
      f32x4 ao = {bi_3, bi_3, bi_3, bi_3};                            \
      ai = mfma16(g0, R0_0, ai); ai = mfma16(g1, R1_0, ai);           \
      af = mfma16(g0, R0_1, af); af = mfma16(g1, R1_1, af);           \
      ag = mfma16(g0, R0_2, ag); ag = mfma16(g1, R1_2, ag);           \
      ao = mfma16(g0, R0_3, ao); ao = mfma16(g1, R1_3, ao);           \
      FINR2(0, WH) FINR2(1, WH) FINR2(2, WH) FINR2(3, WH) }

    for (int it = 0; it <= 256; ++it) {
      if ((it & 31) == 0 && it < 256) { __syncthreads(); }
      if (it >= 1) RSTEP(0, 1, 0)   // even s: h1[s-2] (even idx)
      __syncthreads();
      if (it >= 1) RSTEP(1, 0, 1)   // odd s: h1[s-2] (odd idx)
      __syncthreads();
    }
  }

  // ---- FC head: out[b] = fc_b + sum_j fcW[j] * h1[511][b][j] (parity 1) ----
  if (tid < 16) {
    float s = fcb[0];
    for (int j = 0; j < 50; ++j) {
      const int idx = ((j >> 5) << 9) + (((j >> 2) & 3) << 7) + (tid << 3) +
                      (((j >> 4) & 1) << 2) + (j & 3);
      s += fcW[j] * (float)H1[1][idx];
    }
    out[bbase + tid] = s;
  }
}

extern "C" void kernel_launch(void* const* d_in, const int* in_sizes, int n_in,
                              void* d_out, int out_size, void* d_ws, size_t ws_size,
                              hipStream_t stream) {
  const float* x    = (const float*)d_in[0];
  const float* Wih0 = (const float*)d_in[1];
  const float* Whh0 = (const float*)d_in[2];
  const float* bih0 = (const float*)d_in[3];
  const float* bhh0 = (const float*)d_in[4];
  const float* Wih1 = (const float*)d_in[5];
  const float* Whh1 = (const float*)d_in[6];
  const float* bih1 = (const float*)d_in[7];
  const float* bhh1 = (const float*)d_in[8];
  const float* fcW  = (const float*)d_in[9];
  const float* fcb  = (const float*)d_in[10];
  float* out = (float*)d_out;

  const int B = out_size;          // 4096
  const int blocks = B / 16;       // 256
  lstm2_kernel<<<dim3(blocks), dim3(768), 0, stream>>>(
      x, Wih0, Whh0, bih0, bhh0, Wih1, Whh1, bih1, bhh1, fcW, fcb, out);
}